// Round 9
// baseline (1075.638 us; speedup 1.0000x reference)
//
#include <hip/hip_runtime.h>

#define DIM     64
#define N_EMBED 512
#define N_ROWS  131072   // 32*64*64
#define XPAD    132      // row pitch (bank stagger)

// ---------- prep: ||e_j||^2 ----------
__global__ void prep_se(const float* __restrict__ embed, float* __restrict__ se) {
    int j = blockIdx.x * blockDim.x + threadIdx.x;   // 0..511
    if (j >= N_EMBED) return;
    float s = 0.f;
#pragma unroll
    for (int d = 0; d < DIM; ++d) {
        float e = embed[d * N_EMBED + j];
        s = fmaf(e, e, s);
    }
    se[j] = s;
}

// ---------- assign: LDS-tiled fp32 GEMM-argmin (byte-identical to round 6) ----------
__launch_bounds__(256, 2)
__global__ void vq_assign(const float* __restrict__ input,
                          const float* __restrict__ embed,
                          const float* __restrict__ se,
                          float* __restrict__ out_ind,
                          int*   __restrict__ ind) {
    __shared__ float Xs[64][XPAD];   // [k][row]
    __shared__ float Es[64][XPAD];   // [k][swizzled col]; reused for final reduce
    __shared__ float sxs[128];

    const int t    = threadIdx.x;
    const int row0 = blockIdx.x * 128;
    const int tr   = t >> 4;   // 0..15
    const int tc   = t & 15;   // 0..15
    const int bx   = ((tc >> 2) & 1) * 4;   // XOR on read

    // ---- stage X transposed: Xs[k][i] = input[(row0+i)*64 + k] ----
#pragma unroll
    for (int ph = 0; ph < 8; ++ph) {
        int idx = ph * 256 + t;      // 0..2047
        int row = idx >> 4;          // 0..127
        int kq  = idx & 15;          // 0..15
        float4 v = *reinterpret_cast<const float4*>(
            &input[(size_t)(row0 + row) * 64 + kq * 4]);
        Xs[kq * 4 + 0][row] = v.x;
        Xs[kq * 4 + 1][row] = v.y;
        Xs[kq * 4 + 2][row] = v.z;
        Xs[kq * 4 + 3][row] = v.w;
    }
    __syncthreads();

    // ---- sx per row ----
    if (t < 128) {
        float s = 0.f;
#pragma unroll 8
        for (int k = 0; k < 64; ++k) { float x = Xs[k][t]; s = fmaf(x, x, s); }
        sxs[t] = s;
    }

    float bestd[8], sx[8];
    int   bestj[8];
#pragma unroll
    for (int r = 0; r < 8; ++r) { bestd[r] = INFINITY; bestj[r] = 0; }

    for (int chunk = 0; chunk < 4; ++chunk) {
        const int ccb = chunk * 128;
        __syncthreads();   // prev k-loop done reading Es (also fences sxs/Xs)
#pragma unroll
        for (int ph = 0; ph < 8; ++ph) {
            int idx = ph * 256 + t;  // 0..2047
            int k   = idx >> 5;      // 0..63
            int cq  = idx & 31;      // 0..31
            float4 v = *reinterpret_cast<const float4*>(
                &embed[k * N_EMBED + ccb + cq * 4]);
            // XOR swizzle: block base c=cq*4 -> c ^ (bit5(c)*4)
            *reinterpret_cast<float4*>(&Es[k][(cq * 4) ^ (((cq >> 3) & 1) * 4)]) = v;
        }
        __syncthreads();
        if (chunk == 0) {
#pragma unroll
            for (int r = 0; r < 8; ++r) sx[r] = sxs[tr * 8 + r];
        }

        float acc[8][8];
#pragma unroll
        for (int r = 0; r < 8; ++r)
#pragma unroll
            for (int c = 0; c < 8; ++c) acc[r][c] = 0.f;

#pragma unroll 2
        for (int k = 0; k < 64; ++k) {
            float a[8], b[8];
            *reinterpret_cast<float4*>(&a[0]) = *reinterpret_cast<const float4*>(&Xs[k][tr * 8]);
            *reinterpret_cast<float4*>(&a[4]) = *reinterpret_cast<const float4*>(&Xs[k][tr * 8 + 4]);
            *reinterpret_cast<float4*>(&b[0]) = *reinterpret_cast<const float4*>(&Es[k][(tc * 8) ^ bx]);
            *reinterpret_cast<float4*>(&b[4]) = *reinterpret_cast<const float4*>(&Es[k][(tc * 8 + 4) ^ bx]);
#pragma unroll
            for (int r = 0; r < 8; ++r)
#pragma unroll
                for (int c = 0; c < 8; ++c)
                    acc[r][c] = fmaf(a[r], b[c], acc[r][c]);
        }

        // finalize this chunk: scan cols in increasing j (first-wins ties)
#pragma unroll
        for (int c = 0; c < 8; ++c) {
            int j = ccb + tc * 8 + c;
            float sej = se[j];
#pragma unroll
            for (int r = 0; r < 8; ++r) {
                float d = (sx[r] - 2.f * acc[r][c]) + sej;
                if (d < bestd[r]) { bestd[r] = d; bestj[r] = j; }
            }
        }
    }

    // ---- cross-thread argmin reduce (lexicographic (d, j) == global first-min) ----
    __syncthreads();
    float* rd = &Es[0][0];                 // [128][17]
    int*   rj = (int*)(rd + 128 * 17);     // [128][17]
#pragma unroll
    for (int r = 0; r < 8; ++r) {
        rd[(tr * 8 + r) * 17 + tc] = bestd[r];
        rj[(tr * 8 + r) * 17 + tc] = bestj[r];
    }
    __syncthreads();
    if (t < 128) {
        float bd = rd[t * 17 + 0];
        int   bj = rj[t * 17 + 0];
#pragma unroll
        for (int w = 1; w < 16; ++w) {
            float dw = rd[t * 17 + w];
            int   jw = rj[t * 17 + w];
            if (dw < bd || (dw == bd && jw < bj)) { bd = dw; bj = jw; }
        }
        out_ind[row0 + t] = (float)bj;
        ind[row0 + t]     = bj;
    }
}

// ---------- hist: per-block LDS histogram of ind -> gcount ----------
__launch_bounds__(256)
__global__ void vq_hist(const int* __restrict__ ind, int* __restrict__ gcount) {
    __shared__ int lhist[N_EMBED];
    const int t = threadIdx.x;
    lhist[t] = 0; lhist[t + 256] = 0;
    __syncthreads();
    const int4* ind4 = reinterpret_cast<const int4*>(ind);
    // 64 blocks * 256 threads * 2 int4 = 32768 int4 = 131072 rows
#pragma unroll
    for (int rep = 0; rep < 2; ++rep) {
        int i4 = (blockIdx.x * 2 + rep) * 256 + t;
        int4 v = ind4[i4];
        atomicAdd(&lhist[v.x], 1);
        atomicAdd(&lhist[v.y], 1);
        atomicAdd(&lhist[v.z], 1);
        atomicAdd(&lhist[v.w], 1);
    }
    __syncthreads();
    int v0 = lhist[t], v1 = lhist[t + 256];
    if (v0) atomicAdd(&gcount[t], v0);
    if (v1) atomicAdd(&gcount[t + 256], v1);
}

// ---------- prefix + fin_a: scan gcount -> starts/cursor; ncs + n ----------
__global__ void vq_prefix_fina(const int* __restrict__ gcount,
                               const float* __restrict__ cluster_size,
                               int* __restrict__ starts,
                               int* __restrict__ cursor,
                               float* __restrict__ out_ncs,
                               float* __restrict__ nstore) {
    const int t = threadIdx.x;   // 512 threads, 1 block
    __shared__ int   si[N_EMBED];
    __shared__ float red[N_EMBED];
    int cnt = gcount[t];
    si[t] = cnt;
    __syncthreads();
    // Hillis-Steele inclusive scan
    for (int off = 1; off < N_EMBED; off <<= 1) {
        int add = (t >= off) ? si[t - off] : 0;
        __syncthreads();
        si[t] += add;
        __syncthreads();
    }
    int st = si[t] - cnt;       // exclusive
    starts[t] = st;
    cursor[t] = st;

    float ncs = cluster_size[t] * 0.99f + 0.01f * (float)cnt;
    out_ncs[t] = ncs;
    red[t] = ncs;
    __syncthreads();
    for (int s = 256; s > 0; s >>= 1) {
        if (t < s) red[t] += red[t + s];
        __syncthreads();
    }
    if (t == 0) nstore[0] = red[0];
}

// ---------- scatteridx: bucket row indices by code ----------
__launch_bounds__(256)
__global__ void vq_scatteridx(const int* __restrict__ ind,
                              int* __restrict__ cursor,
                              int* __restrict__ sorted) {
    const int t = threadIdx.x;
    const int i4 = blockIdx.x * 256 + t;   // 128 blocks -> 32768 int4
    const int4* ind4 = reinterpret_cast<const int4*>(ind);
    int4 v = ind4[i4];
    int row = i4 * 4;
    int p0 = atomicAdd(&cursor[v.x], 1); sorted[p0] = row;
    int p1 = atomicAdd(&cursor[v.y], 1); sorted[p1] = row + 1;
    int p2 = atomicAdd(&cursor[v.z], 1); sorted[p2] = row + 2;
    int p3 = atomicAdd(&cursor[v.w], 1); sorted[p3] = row + 3;
}

// ---------- gather: per-code quantize + diff + segment-sum (no gathers, no tables) ----------
__launch_bounds__(256)
__global__ void vq_gather(const float* __restrict__ input,
                          const float* __restrict__ embed,
                          const int* __restrict__ sorted,
                          const int* __restrict__ starts,
                          const int* __restrict__ gcount,
                          float* __restrict__ out_q,
                          float* __restrict__ esum,
                          double* __restrict__ diff_acc) {
    const int j    = blockIdx.x;     // code 0..511
    const int t    = threadIdx.x;
    const int wave = t >> 6;         // 0..3
    const int lane = t & 63;         // dim

    __shared__ float ev[DIM];
    __shared__ float comb[4][DIM];
    __shared__ float wsum[4];

    if (t < DIM) ev[t] = embed[t * N_EMBED + j];   // e_j row (column j of embed)
    __syncthreads();
    const float e = ev[lane];

    const int start = starts[j];
    const int n     = gcount[j];

    float acc = 0.f;    // sum of x[lane] over this wave's rows
    float dsum = 0.f;   // sum of (q-x)^2 over this wave's rows, dim=lane
    for (int q = wave; q < n; q += 4) {
        int row = sorted[start + q];          // wave-uniform -> scalar load
        const float* rp = input + (size_t)row * DIM;
        float x = rp[lane];                   // 256B coalesced per wave
        float d0 = e - x;
        out_q[(size_t)row * DIM + lane] = x + d0;
        acc += x;
        dsum = fmaf(d0, d0, dsum);
    }

    comb[wave][lane] = acc;
    // diff: reduce dsum across 64 lanes, then across waves
    for (int off = 32; off > 0; off >>= 1) dsum += __shfl_down(dsum, off, 64);
    if (lane == 0) wsum[wave] = dsum;
    __syncthreads();
    if (t < DIM) {
        float s = comb[0][t] + comb[1][t] + comb[2][t] + comb[3][t];
        esum[t * N_EMBED + j] = s;            // [d][j] layout, plain store
    }
    if (t == 0) {
        float b = wsum[0] + wsum[1] + wsum[2] + wsum[3];
        atomicAdd(diff_acc, (double)b);
    }
}

// ---------- finalize B: EMA + normalize + diff, fully coalesced ----------
__global__ void fin_b(const float* __restrict__ embed_avg,
                      const float* __restrict__ esum,
                      const float* __restrict__ out_ncs,
                      const float* __restrict__ nstore,
                      const double* __restrict__ diff_acc,
                      float* __restrict__ out_ne,
                      float* __restrict__ out_nea,
                      float* __restrict__ out_diff) {
    int e = blockIdx.x * 512 + threadIdx.x;   // 64 blocks -> 32768
    const float EPSF = 1e-5f;
    float n = nstore[0];
    int j = e & (N_EMBED - 1);
    float ncs = out_ncs[j];
    float cs = (ncs + EPSF) / (n + 512.0f * EPSF) * n;
    float es = embed_avg[e] * 0.99f + 0.01f * esum[e];
    out_nea[e] = es;
    out_ne[e] = es / cs;
    if (e == 0) out_diff[0] = (float)(*diff_acc * (1.0 / 8388608.0));
}

extern "C" void kernel_launch(void* const* d_in, const int* in_sizes, int n_in,
                              void* d_out, int out_size, void* d_ws, size_t ws_size,
                              hipStream_t stream) {
    const float* input        = (const float*)d_in[0];
    const float* embed        = (const float*)d_in[1];
    const float* cluster_size = (const float*)d_in[2];
    const float* embed_avg    = (const float*)d_in[3];

    float* out_q    = (float*)d_out;          // 8388608 floats
    float* out_diff = out_q + 8388608;        // 1
    float* out_ind  = out_diff + 1;           // 131072
    float* out_ne   = out_ind + 131072;       // 32768
    float* out_ncs  = out_ne + 32768;         // 512
    float* out_nea  = out_ncs + 512;          // 32768

    // ws layout (~1.06 MB; round 7 demonstrated ws_size >= 34 MB)
    char*   ws       = (char*)d_ws;
    double* diff_acc = (double*)ws;                      // 8 B
    float*  nstore   = (float*)(ws + 64);                // 1 f32
    int*    gcount   = (int*)(ws + 256);                 // 512 i32 (ends 2304)
    int*    starts   = (int*)(ws + 4096);                // 512 i32
    int*    cursor   = (int*)(ws + 8192);                // 512 i32
    float*  se       = (float*)(ws + 12288);             // 512 f32
    int*    ind      = (int*)(ws + 16384);               // 131072 i32 (512 KB)
    int*    sorted   = (int*)(ws + 16384 + 524288);      // 131072 i32 (512 KB)
    float*  esum     = (float*)(ws + 16384 + 1048576);   // 32768 f32 (128 KB)

    hipMemsetAsync(ws, 0, 4096, stream);   // diff_acc + nstore + gcount

    prep_se<<<2, 256, 0, stream>>>(embed, se);
    vq_assign<<<1024, 256, 0, stream>>>(input, embed, se, out_ind, ind);
    vq_hist<<<64, 256, 0, stream>>>(ind, gcount);
    vq_prefix_fina<<<1, 512, 0, stream>>>(gcount, cluster_size, starts, cursor,
                                          out_ncs, nstore);
    vq_scatteridx<<<128, 256, 0, stream>>>(ind, cursor, sorted);
    vq_gather<<<512, 256, 0, stream>>>(input, embed, sorted, starts, gcount,
                                       out_q, esum, diff_acc);
    fin_b<<<64, 512, 0, stream>>>(embed_avg, esum, out_ncs, nstore, diff_acc,
                                  out_ne, out_nea, out_diff);
}

// Round 10
// 290.129 us; speedup vs baseline: 3.7074x; 3.7074x over previous
//
#include <hip/hip_runtime.h>

#define DIM     64
#define N_EMBED 512
#define N_ROWS  131072   // 32*64*64
#define XPAD    129      // pitch: (4kq+c+row)%32 covers each bank exactly 2x -> conflict-free staging
#define TPITCH  513      // post table pitch: bank=(lane+j)%32 -> 2-way = free

// ---------- prep: ||e_j||^2 and (optional) embed transpose ----------
__global__ void prep_kernel(const float* __restrict__ embed,
                            float* __restrict__ se,
                            float* __restrict__ embed_t,
                            int do_et) {
    int j = blockIdx.x * blockDim.x + threadIdx.x;   // 0..511
    if (j >= N_EMBED) return;
    float s = 0.f;
#pragma unroll
    for (int d = 0; d < DIM; d += 4) {
        float b0 = embed[(d + 0) * N_EMBED + j];
        float b1 = embed[(d + 1) * N_EMBED + j];
        float b2 = embed[(d + 2) * N_EMBED + j];
        float b3 = embed[(d + 3) * N_EMBED + j];
        s = fmaf(b0, b0, s); s = fmaf(b1, b1, s);
        s = fmaf(b2, b2, s); s = fmaf(b3, b3, s);
        if (do_et) {
            float4 v; v.x = b0; v.y = b1; v.z = b2; v.w = b3;
            *reinterpret_cast<float4*>(&embed_t[j * DIM + d]) = v;
        }
    }
    se[j] = s;
}

// ---------- assign: LDS-tiled fp32 GEMM-argmin (round-6 logic, XPAD 132->129) ----------
__launch_bounds__(256, 2)
__global__ void vq_assign(const float* __restrict__ input,
                          const float* __restrict__ embed,
                          const float* __restrict__ se,
                          float* __restrict__ out_ind,
                          int*   __restrict__ ind) {
    __shared__ float Xs[64][XPAD];   // [k][row]
    __shared__ float Es[64][XPAD];   // [k][swizzled col]; reused for final reduce
    __shared__ float sxs[128];

    const int t    = threadIdx.x;
    const int row0 = blockIdx.x * 128;
    const int tr   = t >> 4;   // 0..15
    const int tc   = t & 15;   // 0..15
    const int bx   = ((tc >> 2) & 1) * 4;   // XOR on read

    // ---- stage X transposed: Xs[k][i] = input[(row0+i)*64 + k] ----
#pragma unroll
    for (int ph = 0; ph < 8; ++ph) {
        int idx = ph * 256 + t;      // 0..2047
        int row = idx >> 4;          // 0..127
        int kq  = idx & 15;          // 0..15
        float4 v = *reinterpret_cast<const float4*>(
            &input[(size_t)(row0 + row) * 64 + kq * 4]);
        Xs[kq * 4 + 0][row] = v.x;
        Xs[kq * 4 + 1][row] = v.y;
        Xs[kq * 4 + 2][row] = v.z;
        Xs[kq * 4 + 3][row] = v.w;
    }
    __syncthreads();

    // ---- sx per row ----
    if (t < 128) {
        float s = 0.f;
#pragma unroll 8
        for (int k = 0; k < 64; ++k) { float x = Xs[k][t]; s = fmaf(x, x, s); }
        sxs[t] = s;
    }

    float bestd[8], sx[8];
    int   bestj[8];
#pragma unroll
    for (int r = 0; r < 8; ++r) { bestd[r] = INFINITY; bestj[r] = 0; }

    for (int chunk = 0; chunk < 4; ++chunk) {
        const int ccb = chunk * 128;
        __syncthreads();   // prev k-loop done reading Es (also fences sxs/Xs)
#pragma unroll
        for (int ph = 0; ph < 8; ++ph) {
            int idx = ph * 256 + t;  // 0..2047
            int k   = idx >> 5;      // 0..63
            int cq  = idx & 31;      // 0..31
            float4 v = *reinterpret_cast<const float4*>(
                &embed[k * N_EMBED + ccb + cq * 4]);
            // XOR swizzle: block base c=cq*4 -> c ^ (bit5(c)*4)
            *reinterpret_cast<float4*>(&Es[k][(cq * 4) ^ (((cq >> 3) & 1) * 4)]) = v;
        }
        __syncthreads();
        if (chunk == 0) {
#pragma unroll
            for (int r = 0; r < 8; ++r) sx[r] = sxs[tr * 8 + r];
        }

        float acc[8][8];
#pragma unroll
        for (int r = 0; r < 8; ++r)
#pragma unroll
            for (int c = 0; c < 8; ++c) acc[r][c] = 0.f;

#pragma unroll 2
        for (int k = 0; k < 64; ++k) {
            float a[8], b[8];
            *reinterpret_cast<float4*>(&a[0]) = *reinterpret_cast<const float4*>(&Xs[k][tr * 8]);
            *reinterpret_cast<float4*>(&a[4]) = *reinterpret_cast<const float4*>(&Xs[k][tr * 8 + 4]);
            *reinterpret_cast<float4*>(&b[0]) = *reinterpret_cast<const float4*>(&Es[k][(tc * 8) ^ bx]);
            *reinterpret_cast<float4*>(&b[4]) = *reinterpret_cast<const float4*>(&Es[k][(tc * 8 + 4) ^ bx]);
#pragma unroll
            for (int r = 0; r < 8; ++r)
#pragma unroll
                for (int c = 0; c < 8; ++c)
                    acc[r][c] = fmaf(a[r], b[c], acc[r][c]);
        }

        // finalize this chunk: scan cols in increasing j (first-wins ties)
#pragma unroll
        for (int c = 0; c < 8; ++c) {
            int j = ccb + tc * 8 + c;
            float sej = se[j];
#pragma unroll
            for (int r = 0; r < 8; ++r) {
                float d = (sx[r] - 2.f * acc[r][c]) + sej;
                if (d < bestd[r]) { bestd[r] = d; bestj[r] = j; }
            }
        }
    }

    // ---- cross-thread argmin reduce (lexicographic (d, j) == global first-min) ----
    __syncthreads();
    float* rd = &Es[0][0];                 // [128][17] = 2176 floats, fits in Es (8256)
    int*   rj = (int*)(rd + 128 * 17);     // [128][17]
#pragma unroll
    for (int r = 0; r < 8; ++r) {
        rd[(tr * 8 + r) * 17 + tc] = bestd[r];
        rj[(tr * 8 + r) * 17 + tc] = bestj[r];
    }
    __syncthreads();
    if (t < 128) {
        float bd = rd[t * 17 + 0];
        int   bj = rj[t * 17 + 0];
#pragma unroll
        for (int w = 1; w < 16; ++w) {
            float dw = rd[t * 17 + w];
            int   jw = rj[t * 17 + w];
            if (dw < bd || (dw == bd && jw < bj)) { bd = dw; bj = jw; }
        }
        out_ind[row0 + t] = (float)bj;
        ind[row0 + t]     = bj;
    }
}

// ---------- post2: fused quantize + diff + segment-sum, lane=dim (1 ds_atomic per row) ----------
__launch_bounds__(512, 1)
__global__ void vq_post2(const float* __restrict__ input,
                         const float* __restrict__ embed,
                         const float* __restrict__ embed_t,
                         const int* __restrict__ ind,
                         float* __restrict__ out_q,
                         float* __restrict__ esum,
                         float* __restrict__ counts,
                         double* __restrict__ diff_acc,
                         int have_et) {
    __shared__ float tab[DIM * TPITCH];    // 64*513*4 = 131,328 B
    __shared__ float lcount[N_EMBED];      // 2 KB
    __shared__ float wsum[8];
    const int t    = threadIdx.x;
    const int wave = t >> 6;               // 0..7
    const int lane = t & 63;               // = dim

    for (int i = t; i < DIM * TPITCH; i += 512) tab[i] = 0.f;
    lcount[t] = 0.f;
    __syncthreads();

    // rows: block owns [blockIdx.x*512, +512); wave owns 64 contiguous rows
    const int rbase = blockIdx.x * 512 + wave * 64;
    float dsum = 0.f;

#pragma unroll 4
    for (int it = 0; it < 64; ++it) {
        const int row = rbase + it;
        const int j = ind[row];                              // wave-uniform -> scalar
        const float x = input[(size_t)row * DIM + lane];     // 256B coalesced
        float e;
        if (have_et) e = embed_t[j * DIM + lane];            // 256B coalesced, L2-hot
        else         e = embed[lane * N_EMBED + j];          // strided fallback
        const float d0 = e - x;
        out_q[(size_t)row * DIM + lane] = x + d0;            // 256B coalesced
        dsum = fmaf(d0, d0, dsum);
        atomicAdd(&tab[lane * TPITCH + j], x);               // bank=(lane+j)%32 -> 2-way, free
        if (lane == 0) atomicAdd(&lcount[j], 1.0f);
    }
    __syncthreads();

    // flush: tab -> global esum [d][j] (pitch 512), coalesced atomics
    for (int i = t; i < DIM * N_EMBED; i += 512) {
        const int d = i >> 9, j = i & 511;
        float v = tab[d * TPITCH + j];
        if (v != 0.f) atomicAdd(&esum[i], v);
    }
    {
        float v = lcount[t];
        if (v != 0.f) atomicAdd(&counts[t], v);
    }

    // diff: wave -> block reduce, one f64 atomic per block
    for (int off = 32; off > 0; off >>= 1) dsum += __shfl_down(dsum, off, 64);
    if (lane == 0) wsum[wave] = dsum;
    __syncthreads();
    if (t == 0) {
        float b = 0.f;
#pragma unroll
        for (int w = 0; w < 8; ++w) b += wsum[w];
        atomicAdd(diff_acc, (double)b);
    }
}

// ---------- finalize A: new_cluster_size + n ----------
__global__ void fin_a(const float* __restrict__ cluster_size,
                      const float* __restrict__ counts,
                      float* __restrict__ out_ncs,
                      float* __restrict__ nstore) {
    int t = threadIdx.x;  // 512 threads, 1 block
    float ncs = cluster_size[t] * 0.99f + 0.01f * counts[t];
    out_ncs[t] = ncs;
    __shared__ float red[512];
    red[t] = ncs;
    __syncthreads();
    for (int s = 256; s > 0; s >>= 1) {
        if (t < s) red[t] += red[t + s];
        __syncthreads();
    }
    if (t == 0) nstore[0] = red[0];
}

// ---------- finalize B: EMA + normalize + diff, fully coalesced ----------
__global__ void fin_b(const float* __restrict__ embed_avg,
                      const float* __restrict__ esum,
                      const float* __restrict__ out_ncs,
                      const float* __restrict__ nstore,
                      const double* __restrict__ diff_acc,
                      float* __restrict__ out_ne,
                      float* __restrict__ out_nea,
                      float* __restrict__ out_diff) {
    int e = blockIdx.x * 512 + threadIdx.x;   // 64 blocks -> 32768
    const float EPSF = 1e-5f;
    float n = nstore[0];
    int j = e & (N_EMBED - 1);
    float ncs = out_ncs[j];
    float cs = (ncs + EPSF) / (n + 512.0f * EPSF) * n;
    float es = embed_avg[e] * 0.99f + 0.01f * esum[e];
    out_nea[e] = es;
    out_ne[e] = es / cs;
    if (e == 0) out_diff[0] = (float)(*diff_acc * (1.0 / 8388608.0));
}

extern "C" void kernel_launch(void* const* d_in, const int* in_sizes, int n_in,
                              void* d_out, int out_size, void* d_ws, size_t ws_size,
                              hipStream_t stream) {
    const float* input        = (const float*)d_in[0];
    const float* embed        = (const float*)d_in[1];
    const float* cluster_size = (const float*)d_in[2];
    const float* embed_avg    = (const float*)d_in[3];

    float* out_q    = (float*)d_out;          // 8388608 floats
    float* out_diff = out_q + 8388608;        // 1
    float* out_ind  = out_diff + 1;           // 131072
    float* out_ne   = out_ind + 131072;       // 32768
    float* out_ncs  = out_ne + 32768;         // 512
    float* out_nea  = out_ncs + 512;          // 32768

    // ws layout (~917 KB used)
    char*   ws       = (char*)d_ws;
    double* diff_acc = (double*)ws;                              // [0,8)
    float*  nstore   = (float*)(ws + 64);                        // 1 f32
    float*  counts   = (float*)(ws + 256);                       // 512 f32
    float*  se       = (float*)(ws + 4096);                      // 512 f32
    int*    ind      = (int*)(ws + 8192);                        // 131072 i32 (512 KB)
    float*  esum     = (float*)(ws + 8192 + 524288);             // 32768 f32 (128 KB)
    float*  embed_t  = (float*)(ws + 8192 + 524288 + 131072);    // 32768 f32 (128 KB)

    const size_t need_et = 8192 + 524288 + 131072 + 131072;
    const int have_et = (ws_size >= need_et) ? 1 : 0;

    hipMemsetAsync(ws, 0, 4096, stream);                   // diff_acc + nstore + counts
    hipMemsetAsync(ws + 8192 + 524288, 0, 131072, stream); // esum

    prep_kernel<<<2, 256, 0, stream>>>(embed, se, embed_t, have_et);
    vq_assign<<<1024, 256, 0, stream>>>(input, embed, se, out_ind, ind);
    vq_post2<<<256, 512, 0, stream>>>(input, embed, embed_t, ind, out_q, esum,
                                      counts, diff_acc, have_et);
    fin_a<<<1, 512, 0, stream>>>(cluster_size, counts, out_ncs, nstore);
    fin_b<<<64, 512, 0, stream>>>(embed_avg, esum, out_ncs, nstore, diff_acc,
                                  out_ne, out_nea, out_diff);
}

// Round 11
// 262.477 us; speedup vs baseline: 4.0980x; 1.1054x over previous
//
#include <hip/hip_runtime.h>

#define DIM     64
#define N_EMBED 512
#define N_ROWS  131072   // 32*64*64
#define XPAD    132      // measured-best pitch (R6: 1.035e7 conflicts; R10's 129 doubled them)

// ---------- prep: ||e_j||^2 and embed transpose ----------
__global__ void prep_kernel(const float* __restrict__ embed,
                            float* __restrict__ se,
                            float* __restrict__ embed_t,
                            int do_et) {
    int j = blockIdx.x * blockDim.x + threadIdx.x;   // 0..511
    if (j >= N_EMBED) return;
    float s = 0.f;
#pragma unroll
    for (int d = 0; d < DIM; d += 4) {
        float b0 = embed[(d + 0) * N_EMBED + j];
        float b1 = embed[(d + 1) * N_EMBED + j];
        float b2 = embed[(d + 2) * N_EMBED + j];
        float b3 = embed[(d + 3) * N_EMBED + j];
        s = fmaf(b0, b0, s); s = fmaf(b1, b1, s);
        s = fmaf(b2, b2, s); s = fmaf(b3, b3, s);
        if (do_et) {
            float4 v; v.x = b0; v.y = b1; v.z = b2; v.w = b3;
            *reinterpret_cast<float4*>(&embed_t[j * DIM + d]) = v;
        }
    }
    se[j] = s;
}

// ---------- assign: LDS-tiled fp32 GEMM-argmin (R6 core) + fused quantize/diff epilogue ----------
__launch_bounds__(256, 2)
__global__ void vq_assign(const float* __restrict__ input,
                          const float* __restrict__ embed,
                          const float* __restrict__ se,
                          const float* __restrict__ embed_t,
                          float* __restrict__ out_ind,
                          int*   __restrict__ ind,
                          float* __restrict__ out_q,
                          double* __restrict__ diff_acc,
                          int have_et) {
    __shared__ float Xs[64][XPAD];   // [k][row]
    __shared__ float Es[64][XPAD];   // [k][swizzled col]; reused for final reduce
    __shared__ float sxs[128];
    __shared__ int   bjs[128];
    __shared__ float wsum2[4];

    const int t    = threadIdx.x;
    const int row0 = blockIdx.x * 128;
    const int tr   = t >> 4;   // 0..15
    const int tc   = t & 15;   // 0..15
    const int bx   = ((tc >> 2) & 1) * 4;   // XOR on read

    // ---- stage X transposed: Xs[k][i] = input[(row0+i)*64 + k] ----
#pragma unroll
    for (int ph = 0; ph < 8; ++ph) {
        int idx = ph * 256 + t;      // 0..2047
        int row = idx >> 4;          // 0..127
        int kq  = idx & 15;          // 0..15
        float4 v = *reinterpret_cast<const float4*>(
            &input[(size_t)(row0 + row) * 64 + kq * 4]);
        Xs[kq * 4 + 0][row] = v.x;
        Xs[kq * 4 + 1][row] = v.y;
        Xs[kq * 4 + 2][row] = v.z;
        Xs[kq * 4 + 3][row] = v.w;
    }
    __syncthreads();

    // ---- sx per row ----
    if (t < 128) {
        float s = 0.f;
#pragma unroll 8
        for (int k = 0; k < 64; ++k) { float x = Xs[k][t]; s = fmaf(x, x, s); }
        sxs[t] = s;
    }

    float bestd[8], sx[8];
    int   bestj[8];
#pragma unroll
    for (int r = 0; r < 8; ++r) { bestd[r] = INFINITY; bestj[r] = 0; }

    for (int chunk = 0; chunk < 4; ++chunk) {
        const int ccb = chunk * 128;
        __syncthreads();   // prev k-loop done reading Es (also fences sxs/Xs)
#pragma unroll
        for (int ph = 0; ph < 8; ++ph) {
            int idx = ph * 256 + t;  // 0..2047
            int k   = idx >> 5;      // 0..63
            int cq  = idx & 31;      // 0..31
            float4 v = *reinterpret_cast<const float4*>(
                &embed[k * N_EMBED + ccb + cq * 4]);
            // XOR swizzle: block base c=cq*4 -> c ^ (bit5(c)*4)
            *reinterpret_cast<float4*>(&Es[k][(cq * 4) ^ (((cq >> 3) & 1) * 4)]) = v;
        }
        __syncthreads();
        if (chunk == 0) {
#pragma unroll
            for (int r = 0; r < 8; ++r) sx[r] = sxs[tr * 8 + r];
        }

        float acc[8][8];
#pragma unroll
        for (int r = 0; r < 8; ++r)
#pragma unroll
            for (int c = 0; c < 8; ++c) acc[r][c] = 0.f;

#pragma unroll 2
        for (int k = 0; k < 64; ++k) {
            float a[8], b[8];
            *reinterpret_cast<float4*>(&a[0]) = *reinterpret_cast<const float4*>(&Xs[k][tr * 8]);
            *reinterpret_cast<float4*>(&a[4]) = *reinterpret_cast<const float4*>(&Xs[k][tr * 8 + 4]);
            *reinterpret_cast<float4*>(&b[0]) = *reinterpret_cast<const float4*>(&Es[k][(tc * 8) ^ bx]);
            *reinterpret_cast<float4*>(&b[4]) = *reinterpret_cast<const float4*>(&Es[k][(tc * 8 + 4) ^ bx]);
#pragma unroll
            for (int r = 0; r < 8; ++r)
#pragma unroll
                for (int c = 0; c < 8; ++c)
                    acc[r][c] = fmaf(a[r], b[c], acc[r][c]);
        }

        // finalize this chunk: scan cols in increasing j (first-wins ties)
#pragma unroll
        for (int c = 0; c < 8; ++c) {
            int j = ccb + tc * 8 + c;
            float sej = se[j];
#pragma unroll
            for (int r = 0; r < 8; ++r) {
                float d = (sx[r] - 2.f * acc[r][c]) + sej;
                if (d < bestd[r]) { bestd[r] = d; bestj[r] = j; }
            }
        }
    }

    // ---- cross-thread argmin reduce (lexicographic (d, j) == global first-min) ----
    __syncthreads();
    float* rd = &Es[0][0];                 // [128][17]
    int*   rj = (int*)(rd + 128 * 17);     // [128][17]
#pragma unroll
    for (int r = 0; r < 8; ++r) {
        rd[(tr * 8 + r) * 17 + tc] = bestd[r];
        rj[(tr * 8 + r) * 17 + tc] = bestj[r];
    }
    __syncthreads();
    if (t < 128) {
        float bd = rd[t * 17 + 0];
        int   bj = rj[t * 17 + 0];
#pragma unroll
        for (int w = 1; w < 16; ++w) {
            float dw = rd[t * 17 + w];
            int   jw = rj[t * 17 + w];
            if (dw < bd || (dw == bd && jw < bj)) { bd = dw; bj = jw; }
        }
        out_ind[row0 + t] = (float)bj;
        ind[row0 + t]     = bj;
        bjs[t]            = bj;
    }
    __syncthreads();

    // ---- fused epilogue: quantize_st + diff (input re-read is L2-hot) ----
    const int erow  = t >> 1;          // 0..127
    const int ehalf = t & 1;           // 0/1 -> dims [0,32) / [32,64)
    const int grow  = row0 + erow;
    const int bj2   = bjs[erow];
    const float* xr = input + (size_t)grow * DIM + ehalf * 32;
    float*       oq = out_q + (size_t)grow * DIM + ehalf * 32;
    float dsum = 0.f;

    if (have_et) {
        const float* er = embed_t + (size_t)bj2 * DIM + ehalf * 32;
#pragma unroll
        for (int i = 0; i < 32; i += 4) {
            float4 xv = *reinterpret_cast<const float4*>(xr + i);
            float4 ev = *reinterpret_cast<const float4*>(er + i);
            float t0 = ev.x - xv.x, t1 = ev.y - xv.y;
            float t2 = ev.z - xv.z, t3 = ev.w - xv.w;
            float4 o;
            o.x = xv.x + t0; o.y = xv.y + t1; o.z = xv.z + t2; o.w = xv.w + t3;
            *reinterpret_cast<float4*>(oq + i) = o;
            dsum = fmaf(t0, t0, dsum); dsum = fmaf(t1, t1, dsum);
            dsum = fmaf(t2, t2, dsum); dsum = fmaf(t3, t3, dsum);
        }
    } else {
#pragma unroll
        for (int i = 0; i < 32; ++i) {
            float x = xr[i];
            float e = embed[(ehalf * 32 + i) * N_EMBED + bj2];
            float t0 = e - x;
            oq[i] = x + t0;
            dsum = fmaf(t0, t0, dsum);
        }
    }

    for (int off = 32; off > 0; off >>= 1) dsum += __shfl_down(dsum, off, 64);
    int lane = t & 63, wid = t >> 6;
    if (lane == 0) wsum2[wid] = dsum;
    __syncthreads();
    if (t == 0) {
        float b = wsum2[0] + wsum2[1] + wsum2[2] + wsum2[3];
        atomicAdd(diff_acc, (double)b);
    }
}

// ---------- esum: dim-split segment-sum. block = (rowgroup 0..63, dimgroup 0..7) ----------
// 2048 rows x 8 dims per block; 16.4 KB table -> 4 blocks/CU latency overlap.
__launch_bounds__(256, 4)
__global__ void vq_esum(const float* __restrict__ input,
                        const int* __restrict__ ind,
                        float* __restrict__ esum,
                        int* __restrict__ gcount) {
    const int dimg = blockIdx.x & 7;
    const int rowg = blockIdx.x >> 3;
    const int t    = threadIdx.x;
    const int w    = t >> 6;        // wave 0..3
    const int lane = t & 63;
    const int rloc = lane >> 3;     // 0..7 rows per wave-iter
    const int d    = lane & 7;      // dim within group

    __shared__ float tab[8][513];   // banks (d + j) % 32 -> ~2-way
    __shared__ int   lcnt[N_EMBED];

    for (int i = t; i < 8 * 513; i += 256) (&tab[0][0])[i] = 0.f;
    if (dimg == 0) { lcnt[t] = 0; lcnt[t + 256] = 0; }
    __syncthreads();

    const int rbase = rowg * 2048;
    const int dbase = dimg * 8;

#pragma unroll 4
    for (int it = 0; it < 64; ++it) {
        const int row = rbase + it * 32 + w * 8 + rloc;
        const int j = ind[row];
        const float x = input[(size_t)row * DIM + dbase + d];
        atomicAdd(&tab[d][j], x);
        if (dimg == 0 && d == 0) atomicAdd(&lcnt[j], 1);
    }
    __syncthreads();

    // flush: coalesced global atomics (contention 64-way/address, spread in time)
    for (int i = t; i < 8 * N_EMBED; i += 256) {
        const int dl = i >> 9, j = i & 511;
        float v = tab[dl][j];
        if (v != 0.f) atomicAdd(&esum[(dbase + dl) * N_EMBED + j], v);
    }
    if (dimg == 0) {
        int v0 = lcnt[t];       if (v0) atomicAdd(&gcount[t], v0);
        int v1 = lcnt[t + 256]; if (v1) atomicAdd(&gcount[t + 256], v1);
    }
}

// ---------- finalize A: new_cluster_size + n ----------
__global__ void fin_a(const float* __restrict__ cluster_size,
                      const int* __restrict__ gcount,
                      float* __restrict__ out_ncs,
                      float* __restrict__ nstore) {
    int t = threadIdx.x;  // 512 threads, 1 block
    float ncs = cluster_size[t] * 0.99f + 0.01f * (float)gcount[t];
    out_ncs[t] = ncs;
    __shared__ float red[512];
    red[t] = ncs;
    __syncthreads();
    for (int s = 256; s > 0; s >>= 1) {
        if (t < s) red[t] += red[t + s];
        __syncthreads();
    }
    if (t == 0) nstore[0] = red[0];
}

// ---------- finalize B: EMA + normalize + diff, fully coalesced ----------
__global__ void fin_b(const float* __restrict__ embed_avg,
                      const float* __restrict__ esum,
                      const float* __restrict__ out_ncs,
                      const float* __restrict__ nstore,
                      const double* __restrict__ diff_acc,
                      float* __restrict__ out_ne,
                      float* __restrict__ out_nea,
                      float* __restrict__ out_diff) {
    int e = blockIdx.x * 512 + threadIdx.x;   // 64 blocks -> 32768
    const float EPSF = 1e-5f;
    float n = nstore[0];
    int j = e & (N_EMBED - 1);
    float ncs = out_ncs[j];
    float cs = (ncs + EPSF) / (n + 512.0f * EPSF) * n;
    float es = embed_avg[e] * 0.99f + 0.01f * esum[e];
    out_nea[e] = es;
    out_ne[e] = es / cs;
    if (e == 0) out_diff[0] = (float)(*diff_acc * (1.0 / 8388608.0));
}

extern "C" void kernel_launch(void* const* d_in, const int* in_sizes, int n_in,
                              void* d_out, int out_size, void* d_ws, size_t ws_size,
                              hipStream_t stream) {
    const float* input        = (const float*)d_in[0];
    const float* embed        = (const float*)d_in[1];
    const float* cluster_size = (const float*)d_in[2];
    const float* embed_avg    = (const float*)d_in[3];

    float* out_q    = (float*)d_out;          // 8388608 floats
    float* out_diff = out_q + 8388608;        // 1
    float* out_ind  = out_diff + 1;           // 131072
    float* out_ne   = out_ind + 131072;       // 32768
    float* out_ncs  = out_ne + 32768;         // 512
    float* out_nea  = out_ncs + 512;          // 32768

    // ws layout (~917 KB used)
    char*   ws       = (char*)d_ws;
    double* diff_acc = (double*)ws;                              // [0,8)
    float*  nstore   = (float*)(ws + 64);                        // 1 f32
    int*    gcount   = (int*)(ws + 256);                         // 512 i32 (ends 2304)
    float*  se       = (float*)(ws + 4096);                      // 512 f32
    int*    ind      = (int*)(ws + 8192);                        // 131072 i32 (512 KB)
    float*  esum     = (float*)(ws + 8192 + 524288);             // 32768 f32 (128 KB)
    float*  embed_t  = (float*)(ws + 8192 + 524288 + 131072);    // 32768 f32 (128 KB)

    const size_t need_et = 8192 + 524288 + 131072 + 131072;
    const int have_et = (ws_size >= need_et) ? 1 : 0;

    hipMemsetAsync(ws, 0, 4096, stream);                   // diff_acc + nstore + gcount
    hipMemsetAsync(ws + 8192 + 524288, 0, 131072, stream); // esum

    prep_kernel<<<2, 256, 0, stream>>>(embed, se, embed_t, have_et);
    vq_assign<<<1024, 256, 0, stream>>>(input, embed, se, embed_t, out_ind, ind,
                                        out_q, diff_acc, have_et);
    vq_esum<<<512, 256, 0, stream>>>(input, ind, esum, gcount);
    fin_a<<<1, 512, 0, stream>>>(cluster_size, gcount, out_ncs, nstore);
    fin_b<<<64, 512, 0, stream>>>(embed_avg, esum, out_ncs, nstore, diff_acc,
                                  out_ne, out_nea, out_diff);
}